// Round 8
// baseline (175.173 us; speedup 1.0000x reference)
//
#include <hip/hip_runtime.h>
#include <math.h>

#define Bc 2
#define Tc 1024
#define Cc 1024
#define Hc 16
#define Dc 64
#define DE 128   // extended head dim (64 rope'd + 64 bias features)

typedef unsigned short u16;
typedef __attribute__((ext_vector_type(8))) short bf16x8;   // 8 bf16 in 4 VGPRs
typedef __attribute__((ext_vector_type(4))) float f32x4;

// 0.125 (1/sqrt(D)) * log2(e): prescales q so QK^T scores land in exp2 domain
#define QSCALE 0.1803368801111243f
#define FIXED_M 24.0f   // fixed softmax shift; cancels exactly in o/l

static __device__ inline u16 f2b(float f) {
    unsigned u = __float_as_uint(f);
    u = (u + 0x7fffu + ((u >> 16) & 1u)) >> 16;   // RNE to bf16
    return (u16)u;
}
static __device__ inline float b2f(u16 h) {
    return __uint_as_float((unsigned)h << 16);
}

// async global->LDS, 16B per lane; dest = wave-uniform base + lane*16
typedef __attribute__((address_space(1))) const unsigned int g_u32;
typedef __attribute__((address_space(3))) unsigned int l_u32;
static __device__ __forceinline__ void gll16(const void* g, void* l) {
    __builtin_amdgcn_global_load_lds((g_u32*)g, (l_u32*)l, 16, 0, 0);
}

// ---------------- fused cast fp32 -> bf16 for x, W_attn, W_proj ----------------
__global__ __launch_bounds__(256) void cast_all(
    const float* __restrict__ x, const float* __restrict__ wa, const float* __restrict__ wp,
    u16* __restrict__ xb, u16* __restrict__ wab, u16* __restrict__ wpb)
{
    const int NX = Bc * Tc * Cc;       // 2M
    const int NA = 3 * Cc * Cc;        // 3M
    int i = (blockIdx.x * 256 + threadIdx.x) * 4;
    const float* src; u16* dst; int off;
    if (i < NX)            { src = x;  dst = xb;  off = i; }
    else if (i < NX + NA)  { src = wa; dst = wab; off = i - NX; }
    else                   { src = wp; dst = wpb; off = i - NX - NA; }
    float4 v = *(const float4*)(src + off);
    ushort4 o;
    o.x = f2b(v.x); o.y = f2b(v.y); o.z = f2b(v.z); o.w = f2b(v.w);
    *(ushort4*)(dst + off) = o;
}

// ---------------- C = A * B^T + bias (+resid), bf16 MFMA, double-buffered ----------------
template<int TM, int TN, int WR, int WC, bool OUT_BF16>
__global__ __launch_bounds__(256) void gemm_abt(
    const u16* __restrict__ A, const u16* __restrict__ Bm,
    const float* __restrict__ bias, const float* __restrict__ resid,
    float* __restrict__ outf, u16* __restrict__ outb, int M, int N, int K)
{
    constexpr int WTM = TM / WR;
    constexpr int WTN = TN / WC;
    constexpr int FI = WTM / 16;
    constexpr int FJ = WTN / 16;
    constexpr int ITA = TM / 32;
    constexpr int ITB = TN / 32;
    __shared__ u16 ldsA[2][TM * 64];
    __shared__ u16 ldsB[2][TN * 64];
    const int tid  = threadIdx.x;
    const int wave = tid >> 6;
    const int lane = tid & 63;
    const int l15  = lane & 15;
    const int quad = lane >> 4;
    const int wm = wave / WC;
    const int wn = wave % WC;
    const int tm = blockIdx.y * TM;
    const int tn = blockIdx.x * TN;

    f32x4 acc[FI][FJ] = {};

    auto stage = [&](int buf, int k0) {
#pragma unroll
        for (int it = 0; it < ITA; ++it) {
            int p = it * 256 + tid;
            int row = p >> 3;
            int c = ((p & 7) ^ (row & 7)) * 8;
            gll16(A + (size_t)(tm + row) * K + k0 + c,
                  &ldsA[buf][(it * 256 + (wave << 6)) * 8]);
        }
#pragma unroll
        for (int it = 0; it < ITB; ++it) {
            int p = it * 256 + tid;
            int row = p >> 3;
            int c = ((p & 7) ^ (row & 7)) * 8;
            gll16(Bm + (size_t)(tn + row) * K + k0 + c,
                  &ldsB[buf][(it * 256 + (wave << 6)) * 8]);
        }
    };

    const int NK = K >> 6;
    stage(0, 0);
    for (int ki = 0; ki < NK; ++ki) {
        const int buf = ki & 1;
        __syncthreads();                       // drains vmcnt -> buf ready for all waves
        if (ki + 1 < NK) stage(buf ^ 1, (ki + 1) << 6);
#pragma unroll
        for (int kk = 0; kk < 2; ++kk) {
            bf16x8 af[FI], bf[FJ];
#pragma unroll
            for (int i = 0; i < FI; ++i) {
                int row = wm * WTM + i * 16 + l15;
                int slot = (kk * 4 + quad) ^ (row & 7);
                af[i] = *(const bf16x8*)&ldsA[buf][row * 64 + slot * 8];
            }
#pragma unroll
            for (int j = 0; j < FJ; ++j) {
                int row = wn * WTN + j * 16 + l15;
                int slot = (kk * 4 + quad) ^ (row & 7);
                bf[j] = *(const bf16x8*)&ldsB[buf][row * 64 + slot * 8];
            }
#pragma unroll
            for (int i = 0; i < FI; ++i)
#pragma unroll
                for (int j = 0; j < FJ; ++j)
                    acc[i][j] = __builtin_amdgcn_mfma_f32_16x16x32_bf16(af[i], bf[j], acc[i][j], 0, 0, 0);
        }
    }

#pragma unroll
    for (int i = 0; i < FI; ++i) {
        int row = tm + wm * WTM + i * 16 + quad * 4;    // C/D: row = quad*4+reg
#pragma unroll
        for (int j = 0; j < FJ; ++j) {
            int col = tn + wn * WTN + j * 16 + l15;     //      col = lane&15
            float bb = bias[col];
#pragma unroll
            for (int r = 0; r < 4; ++r) {
                float v = acc[i][j][r] + bb;
                if (resid) v += resid[(size_t)(row + r) * N + col];
                if (OUT_BF16) outb[(size_t)(row + r) * N + col] = f2b(v);
                else          outf[(size_t)(row + r) * N + col] = v;
            }
        }
    }
}

// ---------------- RoPE + bias-feature prep (reads bf16 qkv) ----------------
__global__ __launch_bounds__(256) void prep_kernel(
    const u16* __restrict__ qkv, const float* __restrict__ coords,
    const float* __restrict__ W_rope, const float* __restrict__ W_fb,
    const float* __restrict__ bcos, const float* __restrict__ bsin,
    u16* __restrict__ qe, u16* __restrict__ ke, u16* __restrict__ vt)
{
    const int bt = blockIdx.x;
    const int b = bt >> 10;
    const int t = bt & (Tc - 1);
    const float coord = coords[bt];
    const int tid = threadIdx.x;
    const u16* row = qkv + (size_t)bt * 3072;
    const int e  = tid * 4;
    const int h  = e >> 6;
    const int d0 = e & 63;
    const int m0 = d0 >> 1;

    float th0 = coord * W_rope[m0];
    float th1 = coord * W_rope[m0 + 1];
    float s0 = sinf(th0), c0 = cosf(th0);
    float s1 = sinf(th1), c1 = cosf(th1);

    float q0 = b2f(row[e]), q1 = b2f(row[e + 1]), q2 = b2f(row[e + 2]), q3 = b2f(row[e + 3]);
    float k0 = b2f(row[1024 + e]), k1 = b2f(row[1025 + e]), k2 = b2f(row[1026 + e]), k3 = b2f(row[1027 + e]);
    float v0 = b2f(row[2048 + e]), v1 = b2f(row[2049 + e]), v2 = b2f(row[2050 + e]), v3 = b2f(row[2051 + e]);

    size_t qb = ((size_t)(b * Hc + h) * Tc + t) * DE + d0;
    // q prescaled by 0.125*log2e -> scores come out of the MFMA in exp2 domain
    qe[qb + 0] = f2b((q0 * c0 - q1 * s0) * QSCALE);
    qe[qb + 1] = f2b((q0 * s0 + q1 * c0) * QSCALE);
    qe[qb + 2] = f2b((q2 * c1 - q3 * s1) * QSCALE);
    qe[qb + 3] = f2b((q2 * s1 + q3 * c1) * QSCALE);
    ke[qb + 0] = f2b(k0 * c0 - k1 * s0);
    ke[qb + 1] = f2b(k0 * s0 + k1 * c0);
    ke[qb + 2] = f2b(k2 * c1 - k3 * s1);
    ke[qb + 3] = f2b(k2 * s1 + k3 * c1);

    size_t vb = ((size_t)(b * Hc + h) * Dc + d0) * Tc + t;
    vt[vb]          = f2b(v0);
    vt[vb + Tc]     = f2b(v1);
    vt[vb + 2 * Tc] = f2b(v2);
    vt[vb + 3 * Tc] = f2b(v3);

    // bias features, spread across all 256 threads: thread = (head hh, pair s)
    {
        const int hh = tid >> 4;
        const int s  = tid & 15;
        const int m  = 2 * s;
        float thf0 = coord * W_fb[m],     thf1 = coord * W_fb[m + 1];
        float sn0 = sinf(thf0), cn0 = cosf(thf0);
        float sn1 = sinf(thf1), cn1 = cosf(thf1);
        float bc0 = bcos[m], bs0 = bsin[m], bc1 = bcos[m + 1], bs1 = bsin[m + 1];
        const float SC = 1.41421356237f * QSCALE;
        unsigned u1 = (unsigned)f2b((bc0 * cn0 + bs0 * sn0) * SC) |
                      ((unsigned)f2b((bc1 * cn1 + bs1 * sn1) * SC) << 16);
        unsigned u2 = (unsigned)f2b((bc0 * sn0 - bs0 * cn0) * SC) |
                      ((unsigned)f2b((bc1 * sn1 - bs1 * cn1) * SC) << 16);
        unsigned cp = (unsigned)f2b(cn0) | ((unsigned)f2b(cn1) << 16);
        unsigned sp = (unsigned)f2b(sn0) | ((unsigned)f2b(sn1) << 16);
        size_t base = ((size_t)(b * Hc + hh) * Tc + t) * DE + 64;
        *(unsigned*)&qe[base + m]      = u1;
        *(unsigned*)&qe[base + 32 + m] = u2;
        *(unsigned*)&ke[base + m]      = cp;
        *(unsigned*)&ke[base + 32 + m] = sp;
    }
}

// ---------------- flash attention: 2 waves x 32 q-rows, deferred l ----------------
// grid (T/64, H, B), block 128 = 2 waves; wave owns 32 q rows (2 row-tiles).
// Every K/V fragment read feeds 2 row-tiles of MFMAs; l-reduction deferred to
// a single end-of-kernel shuffle (fixed-M makes per-step partials exact).
__global__ __launch_bounds__(128) void attn_kernel(
    const u16* __restrict__ qe, const u16* __restrict__ ke,
    const u16* __restrict__ vt, u16* __restrict__ yb)
{
    __shared__ u16 ldsK[2][64 * 128];  // 32 KB, swizzled (row&15)
    __shared__ u16 ldsV[2][64 * 64];   // 16 KB, swizzled (row&7)
    __shared__ u16 plds[2][32][72];    //  9 KB wave-private P tiles (32 rows)
    const int tid  = threadIdx.x;
    const int wave = tid >> 6;
    const int lane = tid & 63;
    const int l15  = lane & 15;
    const int quad = lane >> 4;
    const int qt = blockIdx.x * 64;
    const int h  = blockIdx.y;
    const int b  = blockIdx.z;

    const u16* Q  = qe + ((size_t)(b * Hc + h) * Tc) * DE;
    const u16* Kp = ke + ((size_t)(b * Hc + h) * Tc) * DE;
    const u16* Vp = vt + ((size_t)(b * Hc + h) * Dc) * Tc;

    bf16x8 qf[2][4];
#pragma unroll
    for (int i = 0; i < 2; ++i) {
        const u16* qrow = Q + (size_t)(qt + wave * 32 + i * 16 + l15) * DE + quad * 8;
#pragma unroll
        for (int c = 0; c < 4; ++c) qf[i][c] = *(const bf16x8*)(qrow + c * 32);
    }

    auto stageKV = [&](int buf, int kt) {
#pragma unroll
        for (int it = 0; it < 8; ++it) {       // K: 64 rows x 16 chunks = 1024 pos
            int p = it * 128 + tid;
            int row = p >> 4;
            int c = (p & 15) ^ (row & 15);
            gll16(Kp + (size_t)(kt + row) * DE + c * 8,
                  &ldsK[buf][(it * 128 + (wave << 6)) * 8]);
        }
#pragma unroll
        for (int it = 0; it < 4; ++it) {       // V: 64 rows x 8 chunks = 512 pos
            int p = it * 128 + tid;
            int row = p >> 3;
            int c = (p & 7) ^ (row & 7);
            gll16(Vp + (size_t)row * Tc + kt + c * 8,
                  &ldsV[buf][(it * 128 + (wave << 6)) * 8]);
        }
    };

    f32x4 o[2][4] = {};
    float lrow[2][4] = {};

    stageKV(0, 0);
    for (int ki = 0; ki < Tc / 64; ++ki) {
        const int buf = ki & 1;
        __syncthreads();                       // buf ready (implicit vmcnt drain)
        if (ki + 1 < Tc / 64) stageKV(buf ^ 1, (ki + 1) * 64);

        f32x4 sf[2][4] = {};
#pragma unroll
        for (int f = 0; f < 4; ++f) {
#pragma unroll
            for (int c = 0; c < 4; ++c) {
                int row = f * 16 + l15;
                int slot = (c * 4 + quad) ^ (row & 15);
                bf16x8 kf = *(const bf16x8*)&ldsK[buf][row * 128 + slot * 8];
#pragma unroll
                for (int i = 0; i < 2; ++i)
                    sf[i][f] = __builtin_amdgcn_mfma_f32_16x16x32_bf16(qf[i][c], kf, sf[i][f], 0, 0, 0);
            }
        }
        // p = exp2(s - M), fixed M cancels in o/l; truncate to bf16, accumulate
        // per-lane partial l in registers (reduced once at the end).
#pragma unroll
        for (int i = 0; i < 2; ++i)
#pragma unroll
            for (int f = 0; f < 4; ++f)
#pragma unroll
                for (int r = 0; r < 4; ++r) {
                    float p = __builtin_amdgcn_exp2f(sf[i][f][r] - FIXED_M);
                    u16 tp = (u16)(__float_as_uint(p) >> 16);
                    plds[wave][i * 16 + quad * 4 + r][f * 16 + l15] = tp;
                    lrow[i][r] += b2f(tp);
                }

#pragma unroll
        for (int c = 0; c < 2; ++c) {
            bf16x8 pa[2];
#pragma unroll
            for (int i = 0; i < 2; ++i)
                pa[i] = *(const bf16x8*)&plds[wave][i * 16 + l15][c * 32 + quad * 8];
#pragma unroll
            for (int df = 0; df < 4; ++df) {
                int row = df * 16 + l15;
                int slot = (c * 4 + quad) ^ (row & 7);
                bf16x8 vf = *(const bf16x8*)&ldsV[buf][row * 64 + slot * 8];
#pragma unroll
                for (int i = 0; i < 2; ++i)
                    o[i][df] = __builtin_amdgcn_mfma_f32_16x16x32_bf16(pa[i], vf, o[i][df], 0, 0, 0);
            }
        }
    }

    // single deferred l-reduction over the 16-lane column groups
    float rl[2][4];
#pragma unroll
    for (int i = 0; i < 2; ++i)
#pragma unroll
        for (int r = 0; r < 4; ++r) {
            float v = lrow[i][r];
#pragma unroll
            for (int off = 1; off < 16; off <<= 1) v += __shfl_xor(v, off);
            rl[i][r] = 1.0f / v;
        }
#pragma unroll
    for (int i = 0; i < 2; ++i)
#pragma unroll
        for (int df = 0; df < 4; ++df)
#pragma unroll
            for (int r = 0; r < 4; ++r) {
                int t = qt + wave * 32 + i * 16 + quad * 4 + r;
                int d = df * 16 + l15;
                yb[((size_t)b * Tc + t) * Cc + h * Dc + d] = f2b(o[i][df][r] * rl[i][r]);
            }
}

extern "C" void kernel_launch(void* const* d_in, const int* in_sizes, int n_in,
                              void* d_out, int out_size, void* d_ws, size_t ws_size,
                              hipStream_t stream) {
    const float* x      = (const float*)d_in[0];
    const float* coords = (const float*)d_in[1];
    const float* W_attn = (const float*)d_in[2];
    const float* b_attn = (const float*)d_in[3];
    const float* W_proj = (const float*)d_in[4];
    const float* b_proj = (const float*)d_in[5];
    const float* W_rope = (const float*)d_in[6];
    const float* W_fb   = (const float*)d_in[7];
    const float* bcos   = (const float*)d_in[8];
    const float* bsin   = (const float*)d_in[9];
    float* out = (float*)d_out;

    char* w = (char*)d_ws;
    const size_t MB = 1024 * 1024;
    u16* xb     = (u16*)(w + 0);          //  4 MB: x bf16
    u16* wab    = (u16*)(w + 4 * MB);     //  6 MB: W_attn bf16
    u16* wpb    = (u16*)(w + 10 * MB);    //  2 MB: W_proj bf16
    u16* qkvb16 = (u16*)(w + 12 * MB);    // 12 MB: qkv bf16
    u16* qext   = (u16*)(w + 24 * MB);    //  8 MB: q_ext (prescaled)
    u16* kext   = (u16*)(w + 32 * MB);    //  8 MB: k_ext
    u16* vtw    = (u16*)(w + 40 * MB);    //  4 MB: v^T
    u16* yb     = (u16*)(w + 44 * MB);    //  4 MB: attn out bf16

    const int NALL = (Bc * Tc * Cc + 3 * Cc * Cc + Cc * Cc) / 4;
    cast_all<<<NALL / 256, 256, 0, stream>>>(x, W_attn, W_proj, xb, wab, wpb);

    // 64x128 tile: 768 blocks = 3/CU exact, 48 KB LDS -> 3 blocks/CU resident
    dim3 g1(3 * Cc / 128, Bc * Tc / 64);
    gemm_abt<64, 128, 2, 2, true><<<g1, 256, 0, stream>>>(
        xb, wab, b_attn, nullptr, nullptr, qkvb16, Bc * Tc, 3 * Cc, Cc);

    prep_kernel<<<Bc * Tc, 256, 0, stream>>>(qkvb16, coords, W_rope, W_fb, bcos, bsin, qext, kext, vtw);

    dim3 g2(Tc / 64, Hc, Bc);
    attn_kernel<<<g2, 128, 0, stream>>>(qext, kext, vtw, yb);

    dim3 g3(Cc / 64, Bc * Tc / 64);
    gemm_abt<64, 64, 2, 2, false><<<g3, 256, 0, stream>>>(
        yb, wpb, b_proj, x, out, nullptr, Bc * Tc, Cc, Cc);
}

// Round 9
// 171.708 us; speedup vs baseline: 1.0202x; 1.0202x over previous
//
#include <hip/hip_runtime.h>
#include <math.h>

#define Bc 2
#define Tc 1024
#define Cc 1024
#define Hc 16
#define Dc 64
#define DE 128   // extended head dim (64 rope'd + 64 bias features)

typedef unsigned short u16;
typedef __attribute__((ext_vector_type(8))) short bf16x8;   // 8 bf16 in 4 VGPRs
typedef __attribute__((ext_vector_type(4))) float f32x4;

// 0.125 (1/sqrt(D)) * log2(e): prescales q so QK^T scores land in exp2 domain
#define QSCALE 0.1803368801111243f
#define FIXED_M 24.0f   // fixed softmax shift; cancels exactly in o/l

static __device__ inline u16 f2b(float f) {
    unsigned u = __float_as_uint(f);
    u = (u + 0x7fffu + ((u >> 16) & 1u)) >> 16;   // RNE to bf16
    return (u16)u;
}
static __device__ inline float b2f(u16 h) {
    return __uint_as_float((unsigned)h << 16);
}

// async global->LDS, 16B per lane; dest = wave-uniform base + lane*16
typedef __attribute__((address_space(1))) const unsigned int g_u32;
typedef __attribute__((address_space(3))) unsigned int l_u32;
static __device__ __forceinline__ void gll16(const void* g, void* l) {
    __builtin_amdgcn_global_load_lds((g_u32*)g, (l_u32*)l, 16, 0, 0);
}

// ---------------- fused cast fp32 -> bf16 for x, W_attn, W_proj ----------------
__global__ __launch_bounds__(256) void cast_all(
    const float* __restrict__ x, const float* __restrict__ wa, const float* __restrict__ wp,
    u16* __restrict__ xb, u16* __restrict__ wab, u16* __restrict__ wpb)
{
    const int NX = Bc * Tc * Cc;       // 2M
    const int NA = 3 * Cc * Cc;        // 3M
    int i = (blockIdx.x * 256 + threadIdx.x) * 4;
    const float* src; u16* dst; int off;
    if (i < NX)            { src = x;  dst = xb;  off = i; }
    else if (i < NX + NA)  { src = wa; dst = wab; off = i - NX; }
    else                   { src = wp; dst = wpb; off = i - NX - NA; }
    float4 v = *(const float4*)(src + off);
    ushort4 o;
    o.x = f2b(v.x); o.y = f2b(v.y); o.z = f2b(v.z); o.w = f2b(v.w);
    *(ushort4*)(dst + off) = o;
}

// ---------------- C = A * B^T + bias (+resid), bf16 MFMA, double-buffered ----------------
template<int TM, int TN, int WR, int WC, bool OUT_BF16>
__global__ __launch_bounds__(256) void gemm_abt(
    const u16* __restrict__ A, const u16* __restrict__ Bm,
    const float* __restrict__ bias, const float* __restrict__ resid,
    float* __restrict__ outf, u16* __restrict__ outb, int M, int N, int K)
{
    constexpr int WTM = TM / WR;
    constexpr int WTN = TN / WC;
    constexpr int FI = WTM / 16;
    constexpr int FJ = WTN / 16;
    constexpr int ITA = TM / 32;
    constexpr int ITB = TN / 32;
    __shared__ u16 ldsA[2][TM * 64];
    __shared__ u16 ldsB[2][TN * 64];
    const int tid  = threadIdx.x;
    const int wave = tid >> 6;
    const int lane = tid & 63;
    const int l15  = lane & 15;
    const int quad = lane >> 4;
    const int wm = wave / WC;
    const int wn = wave % WC;
    const int tm = blockIdx.y * TM;
    const int tn = blockIdx.x * TN;

    f32x4 acc[FI][FJ] = {};

    auto stage = [&](int buf, int k0) {
#pragma unroll
        for (int it = 0; it < ITA; ++it) {
            int p = it * 256 + tid;
            int row = p >> 3;
            int c = ((p & 7) ^ (row & 7)) * 8;
            gll16(A + (size_t)(tm + row) * K + k0 + c,
                  &ldsA[buf][(it * 256 + (wave << 6)) * 8]);
        }
#pragma unroll
        for (int it = 0; it < ITB; ++it) {
            int p = it * 256 + tid;
            int row = p >> 3;
            int c = ((p & 7) ^ (row & 7)) * 8;
            gll16(Bm + (size_t)(tn + row) * K + k0 + c,
                  &ldsB[buf][(it * 256 + (wave << 6)) * 8]);
        }
    };

    const int NK = K >> 6;
    stage(0, 0);
    for (int ki = 0; ki < NK; ++ki) {
        const int buf = ki & 1;
        __syncthreads();                       // drains vmcnt -> buf ready for all waves
        if (ki + 1 < NK) stage(buf ^ 1, (ki + 1) << 6);
#pragma unroll
        for (int kk = 0; kk < 2; ++kk) {
            bf16x8 af[FI], bf[FJ];
#pragma unroll
            for (int i = 0; i < FI; ++i) {
                int row = wm * WTM + i * 16 + l15;
                int slot = (kk * 4 + quad) ^ (row & 7);
                af[i] = *(const bf16x8*)&ldsA[buf][row * 64 + slot * 8];
            }
#pragma unroll
            for (int j = 0; j < FJ; ++j) {
                int row = wn * WTN + j * 16 + l15;
                int slot = (kk * 4 + quad) ^ (row & 7);
                bf[j] = *(const bf16x8*)&ldsB[buf][row * 64 + slot * 8];
            }
#pragma unroll
            for (int i = 0; i < FI; ++i)
#pragma unroll
                for (int j = 0; j < FJ; ++j)
                    acc[i][j] = __builtin_amdgcn_mfma_f32_16x16x32_bf16(af[i], bf[j], acc[i][j], 0, 0, 0);
        }
    }

#pragma unroll
    for (int i = 0; i < FI; ++i) {
        int row = tm + wm * WTM + i * 16 + quad * 4;    // C/D: row = quad*4+reg
#pragma unroll
        for (int j = 0; j < FJ; ++j) {
            int col = tn + wn * WTN + j * 16 + l15;     //      col = lane&15
            float bb = bias[col];
#pragma unroll
            for (int r = 0; r < 4; ++r) {
                float v = acc[i][j][r] + bb;
                if (resid) v += resid[(size_t)(row + r) * N + col];
                if (OUT_BF16) outb[(size_t)(row + r) * N + col] = f2b(v);
                else          outf[(size_t)(row + r) * N + col] = v;
            }
        }
    }
}

// ---------------- RoPE + bias-feature prep (reads bf16 qkv) ----------------
__global__ __launch_bounds__(256) void prep_kernel(
    const u16* __restrict__ qkv, const float* __restrict__ coords,
    const float* __restrict__ W_rope, const float* __restrict__ W_fb,
    const float* __restrict__ bcos, const float* __restrict__ bsin,
    u16* __restrict__ qe, u16* __restrict__ ke, u16* __restrict__ vt)
{
    const int bt = blockIdx.x;
    const int b = bt >> 10;
    const int t = bt & (Tc - 1);
    const float coord = coords[bt];
    const int tid = threadIdx.x;
    const u16* row = qkv + (size_t)bt * 3072;
    const int e  = tid * 4;
    const int h  = e >> 6;
    const int d0 = e & 63;
    const int m0 = d0 >> 1;

    float th0 = coord * W_rope[m0];
    float th1 = coord * W_rope[m0 + 1];
    float s0 = sinf(th0), c0 = cosf(th0);
    float s1 = sinf(th1), c1 = cosf(th1);

    float q0 = b2f(row[e]), q1 = b2f(row[e + 1]), q2 = b2f(row[e + 2]), q3 = b2f(row[e + 3]);
    float k0 = b2f(row[1024 + e]), k1 = b2f(row[1025 + e]), k2 = b2f(row[1026 + e]), k3 = b2f(row[1027 + e]);
    float v0 = b2f(row[2048 + e]), v1 = b2f(row[2049 + e]), v2 = b2f(row[2050 + e]), v3 = b2f(row[2051 + e]);

    size_t qb = ((size_t)(b * Hc + h) * Tc + t) * DE + d0;
    // q prescaled by 0.125*log2e -> scores come out of the MFMA in exp2 domain
    qe[qb + 0] = f2b((q0 * c0 - q1 * s0) * QSCALE);
    qe[qb + 1] = f2b((q0 * s0 + q1 * c0) * QSCALE);
    qe[qb + 2] = f2b((q2 * c1 - q3 * s1) * QSCALE);
    qe[qb + 3] = f2b((q2 * s1 + q3 * c1) * QSCALE);
    ke[qb + 0] = f2b(k0 * c0 - k1 * s0);
    ke[qb + 1] = f2b(k0 * s0 + k1 * c0);
    ke[qb + 2] = f2b(k2 * c1 - k3 * s1);
    ke[qb + 3] = f2b(k2 * s1 + k3 * c1);

    size_t vb = ((size_t)(b * Hc + h) * Dc + d0) * Tc + t;
    vt[vb]          = f2b(v0);
    vt[vb + Tc]     = f2b(v1);
    vt[vb + 2 * Tc] = f2b(v2);
    vt[vb + 3 * Tc] = f2b(v3);

    // bias features, spread across all 256 threads: thread = (head hh, pair s)
    {
        const int hh = tid >> 4;
        const int s  = tid & 15;
        const int m  = 2 * s;
        float thf0 = coord * W_fb[m],     thf1 = coord * W_fb[m + 1];
        float sn0 = sinf(thf0), cn0 = cosf(thf0);
        float sn1 = sinf(thf1), cn1 = cosf(thf1);
        float bc0 = bcos[m], bs0 = bsin[m], bc1 = bcos[m + 1], bs1 = bsin[m + 1];
        const float SC = 1.41421356237f * QSCALE;
        unsigned u1 = (unsigned)f2b((bc0 * cn0 + bs0 * sn0) * SC) |
                      ((unsigned)f2b((bc1 * cn1 + bs1 * sn1) * SC) << 16);
        unsigned u2 = (unsigned)f2b((bc0 * sn0 - bs0 * cn0) * SC) |
                      ((unsigned)f2b((bc1 * sn1 - bs1 * cn1) * SC) << 16);
        unsigned cp = (unsigned)f2b(cn0) | ((unsigned)f2b(cn1) << 16);
        unsigned sp = (unsigned)f2b(sn0) | ((unsigned)f2b(sn1) << 16);
        size_t base = ((size_t)(b * Hc + hh) * Tc + t) * DE + 64;
        *(unsigned*)&qe[base + m]      = u1;
        *(unsigned*)&qe[base + 32 + m] = u2;
        *(unsigned*)&ke[base + m]      = cp;
        *(unsigned*)&ke[base + 32 + m] = sp;
    }
}

// ---------------- flash attention: q-tile 128, 4 waves x 32 q-rows ----------------
// grid (H*B, T/128) -> 256 blocks, 1/CU, 8 waves/CU (2/SIMD). Each K/V frag read
// feeds 2 row-tiles of MFMAs; l deferred to one end-of-kernel shuffle. Grid
// ordering puts the 8 t-tiles of one head at linear stride 32 -> same XCD (L2).
__global__ __launch_bounds__(256) void attn_kernel(
    const u16* __restrict__ qe, const u16* __restrict__ ke,
    const u16* __restrict__ vt, u16* __restrict__ yb)
{
    __shared__ u16 ldsK[2][64 * 128];  // 32 KB, swizzled (row&15)
    __shared__ u16 ldsV[2][64 * 64];   // 16 KB, swizzled (row&7)
    __shared__ u16 plds[4][32][72];    // 18 KB wave-private P tiles (32 rows)
    const int tid  = threadIdx.x;
    const int wave = tid >> 6;
    const int lane = tid & 63;
    const int l15  = lane & 15;
    const int quad = lane >> 4;
    const int h  = blockIdx.x & 15;
    const int b  = blockIdx.x >> 4;
    const int qt = blockIdx.y * 128;

    const u16* Q  = qe + ((size_t)(b * Hc + h) * Tc) * DE;
    const u16* Kp = ke + ((size_t)(b * Hc + h) * Tc) * DE;
    const u16* Vp = vt + ((size_t)(b * Hc + h) * Dc) * Tc;

    bf16x8 qf[2][4];
#pragma unroll
    for (int i = 0; i < 2; ++i) {
        const u16* qrow = Q + (size_t)(qt + wave * 32 + i * 16 + l15) * DE + quad * 8;
#pragma unroll
        for (int c = 0; c < 4; ++c) qf[i][c] = *(const bf16x8*)(qrow + c * 32);
    }

    auto stageKV = [&](int buf, int kt) {
#pragma unroll
        for (int it = 0; it < 4; ++it) {       // K: 64 rows x 16 chunks = 1024 pos
            int p = it * 256 + tid;
            int row = p >> 4;
            int c = (p & 15) ^ (row & 15);
            gll16(Kp + (size_t)(kt + row) * DE + c * 8,
                  &ldsK[buf][(it * 256 + (wave << 6)) * 8]);
        }
#pragma unroll
        for (int it = 0; it < 2; ++it) {       // V: 64 rows x 8 chunks = 512 pos
            int p = it * 256 + tid;
            int row = p >> 3;
            int c = (p & 7) ^ (row & 7);
            gll16(Vp + (size_t)row * Tc + kt + c * 8,
                  &ldsV[buf][(it * 256 + (wave << 6)) * 8]);
        }
    };

    f32x4 o[2][4] = {};
    float lrow[2][4] = {};

    stageKV(0, 0);
    for (int ki = 0; ki < Tc / 64; ++ki) {
        const int buf = ki & 1;
        __syncthreads();                       // buf ready (implicit vmcnt drain)
        if (ki + 1 < Tc / 64) stageKV(buf ^ 1, (ki + 1) * 64);

        f32x4 sf[2][4] = {};
#pragma unroll
        for (int f = 0; f < 4; ++f) {
#pragma unroll
            for (int c = 0; c < 4; ++c) {
                int row = f * 16 + l15;
                int slot = (c * 4 + quad) ^ (row & 15);
                bf16x8 kf = *(const bf16x8*)&ldsK[buf][row * 128 + slot * 8];
#pragma unroll
                for (int i = 0; i < 2; ++i)
                    sf[i][f] = __builtin_amdgcn_mfma_f32_16x16x32_bf16(qf[i][c], kf, sf[i][f], 0, 0, 0);
            }
        }
        // p = exp2(s - M), fixed M cancels in o/l; truncate to bf16, accumulate
        // per-lane partial l in registers (reduced once at the end).
#pragma unroll
        for (int i = 0; i < 2; ++i)
#pragma unroll
            for (int f = 0; f < 4; ++f)
#pragma unroll
                for (int r = 0; r < 4; ++r) {
                    float p = __builtin_amdgcn_exp2f(sf[i][f][r] - FIXED_M);
                    u16 tp = (u16)(__float_as_uint(p) >> 16);
                    plds[wave][i * 16 + quad * 4 + r][f * 16 + l15] = tp;
                    lrow[i][r] += b2f(tp);
                }

#pragma unroll
        for (int c = 0; c < 2; ++c) {
            bf16x8 pa[2];
#pragma unroll
            for (int i = 0; i < 2; ++i)
                pa[i] = *(const bf16x8*)&plds[wave][i * 16 + l15][c * 32 + quad * 8];
#pragma unroll
            for (int df = 0; df < 4; ++df) {
                int row = df * 16 + l15;
                int slot = (c * 4 + quad) ^ (row & 7);
                bf16x8 vf = *(const bf16x8*)&ldsV[buf][row * 64 + slot * 8];
#pragma unroll
                for (int i = 0; i < 2; ++i)
                    o[i][df] = __builtin_amdgcn_mfma_f32_16x16x32_bf16(pa[i], vf, o[i][df], 0, 0, 0);
            }
        }
    }

    // single deferred l-reduction over the 16-lane column groups
    float rl[2][4];
#pragma unroll
    for (int i = 0; i < 2; ++i)
#pragma unroll
        for (int r = 0; r < 4; ++r) {
            float v = lrow[i][r];
#pragma unroll
            for (int off = 1; off < 16; off <<= 1) v += __shfl_xor(v, off);
            rl[i][r] = 1.0f / v;
        }
#pragma unroll
    for (int i = 0; i < 2; ++i)
#pragma unroll
        for (int df = 0; df < 4; ++df)
#pragma unroll
            for (int r = 0; r < 4; ++r) {
                int t = qt + wave * 32 + i * 16 + quad * 4 + r;
                int d = df * 16 + l15;
                yb[((size_t)b * Tc + t) * Cc + h * Dc + d] = f2b(o[i][df][r] * rl[i][r]);
            }
}

extern "C" void kernel_launch(void* const* d_in, const int* in_sizes, int n_in,
                              void* d_out, int out_size, void* d_ws, size_t ws_size,
                              hipStream_t stream) {
    const float* x      = (const float*)d_in[0];
    const float* coords = (const float*)d_in[1];
    const float* W_attn = (const float*)d_in[2];
    const float* b_attn = (const float*)d_in[3];
    const float* W_proj = (const float*)d_in[4];
    const float* b_proj = (const float*)d_in[5];
    const float* W_rope = (const float*)d_in[6];
    const float* W_fb   = (const float*)d_in[7];
    const float* bcos   = (const float*)d_in[8];
    const float* bsin   = (const float*)d_in[9];
    float* out = (float*)d_out;

    char* w = (char*)d_ws;
    const size_t MB = 1024 * 1024;
    u16* xb     = (u16*)(w + 0);          //  4 MB: x bf16
    u16* wab    = (u16*)(w + 4 * MB);     //  6 MB: W_attn bf16
    u16* wpb    = (u16*)(w + 10 * MB);    //  2 MB: W_proj bf16
    u16* qkvb16 = (u16*)(w + 12 * MB);    // 12 MB: qkv bf16
    u16* qext   = (u16*)(w + 24 * MB);    //  8 MB: q_ext (prescaled)
    u16* kext   = (u16*)(w + 32 * MB);    //  8 MB: k_ext
    u16* vtw    = (u16*)(w + 40 * MB);    //  4 MB: v^T
    u16* yb     = (u16*)(w + 44 * MB);    //  4 MB: attn out bf16

    const int NALL = (Bc * Tc * Cc + 3 * Cc * Cc + Cc * Cc) / 4;
    cast_all<<<NALL / 256, 256, 0, stream>>>(x, W_attn, W_proj, xb, wab, wpb);

    // 64x128 tile: 768 blocks = 3/CU exact, 48 KB LDS -> 3 blocks/CU resident
    dim3 g1(3 * Cc / 128, Bc * Tc / 64);
    gemm_abt<64, 128, 2, 2, true><<<g1, 256, 0, stream>>>(
        xb, wab, b_attn, nullptr, nullptr, qkvb16, Bc * Tc, 3 * Cc, Cc);

    prep_kernel<<<Bc * Tc, 256, 0, stream>>>(qkvb16, coords, W_rope, W_fb, bcos, bsin, qext, kext, vtw);

    dim3 g2(Hc * Bc, Tc / 128);
    attn_kernel<<<g2, 256, 0, stream>>>(qext, kext, vtw, yb);

    dim3 g3(Cc / 64, Bc * Tc / 64);
    gemm_abt<64, 64, 2, 2, false><<<g3, 256, 0, stream>>>(
        yb, wpb, b_proj, x, out, nullptr, Bc * Tc, Cc, Cc);
}

// Round 10
// 169.631 us; speedup vs baseline: 1.0327x; 1.0122x over previous
//
#include <hip/hip_runtime.h>
#include <math.h>

#define Bc 2
#define Tc 1024
#define Cc 1024
#define Hc 16
#define Dc 64
#define DE 128   // extended head dim (64 rope'd + 64 bias features)

typedef unsigned short u16;
typedef __attribute__((ext_vector_type(8))) short bf16x8;   // 8 bf16 in 4 VGPRs
typedef __attribute__((ext_vector_type(4))) float f32x4;
typedef __attribute__((ext_vector_type(16))) float f32x16;

// 0.125 (1/sqrt(D)) * log2(e): prescales q so QK^T scores land in exp2 domain
#define QSCALE 0.1803368801111243f
#define FIXED_M 24.0f   // fixed softmax shift; cancels exactly in o/l

static __device__ inline u16 f2b(float f) {
    unsigned u = __float_as_uint(f);
    u = (u + 0x7fffu + ((u >> 16) & 1u)) >> 16;   // RNE to bf16
    return (u16)u;
}
static __device__ inline float b2f(u16 h) {
    return __uint_as_float((unsigned)h << 16);
}

// async global->LDS, 16B per lane; dest = wave-uniform base + lane*16
typedef __attribute__((address_space(1))) const unsigned int g_u32;
typedef __attribute__((address_space(3))) unsigned int l_u32;
static __device__ __forceinline__ void gll16(const void* g, void* l) {
    __builtin_amdgcn_global_load_lds((g_u32*)g, (l_u32*)l, 16, 0, 0);
}

// ---------------- fused cast fp32 -> bf16 for x, W_attn, W_proj ----------------
__global__ __launch_bounds__(256) void cast_all(
    const float* __restrict__ x, const float* __restrict__ wa, const float* __restrict__ wp,
    u16* __restrict__ xb, u16* __restrict__ wab, u16* __restrict__ wpb)
{
    const int NX = Bc * Tc * Cc;       // 2M
    const int NA = 3 * Cc * Cc;        // 3M
    int i = (blockIdx.x * 256 + threadIdx.x) * 4;
    const float* src; u16* dst; int off;
    if (i < NX)            { src = x;  dst = xb;  off = i; }
    else if (i < NX + NA)  { src = wa; dst = wab; off = i - NX; }
    else                   { src = wp; dst = wpb; off = i - NX - NA; }
    float4 v = *(const float4*)(src + off);
    ushort4 o;
    o.x = f2b(v.x); o.y = f2b(v.y); o.z = f2b(v.z); o.w = f2b(v.w);
    *(ushort4*)(dst + off) = o;
}

// ---------------- C = A * B^T + bias (+resid), bf16 MFMA, double-buffered ----------------
template<int TM, int TN, int WR, int WC, bool OUT_BF16>
__global__ __launch_bounds__(256) void gemm_abt(
    const u16* __restrict__ A, const u16* __restrict__ Bm,
    const float* __restrict__ bias, const float* __restrict__ resid,
    float* __restrict__ outf, u16* __restrict__ outb, int M, int N, int K)
{
    constexpr int WTM = TM / WR;
    constexpr int WTN = TN / WC;
    constexpr int FI = WTM / 16;
    constexpr int FJ = WTN / 16;
    constexpr int ITA = TM / 32;
    constexpr int ITB = TN / 32;
    __shared__ u16 ldsA[2][TM * 64];
    __shared__ u16 ldsB[2][TN * 64];
    const int tid  = threadIdx.x;
    const int wave = tid >> 6;
    const int lane = tid & 63;
    const int l15  = lane & 15;
    const int quad = lane >> 4;
    const int wm = wave / WC;
    const int wn = wave % WC;
    const int tm = blockIdx.y * TM;
    const int tn = blockIdx.x * TN;

    f32x4 acc[FI][FJ] = {};

    auto stage = [&](int buf, int k0) {
#pragma unroll
        for (int it = 0; it < ITA; ++it) {
            int p = it * 256 + tid;
            int row = p >> 3;
            int c = ((p & 7) ^ (row & 7)) * 8;
            gll16(A + (size_t)(tm + row) * K + k0 + c,
                  &ldsA[buf][(it * 256 + (wave << 6)) * 8]);
        }
#pragma unroll
        for (int it = 0; it < ITB; ++it) {
            int p = it * 256 + tid;
            int row = p >> 3;
            int c = ((p & 7) ^ (row & 7)) * 8;
            gll16(Bm + (size_t)(tn + row) * K + k0 + c,
                  &ldsB[buf][(it * 256 + (wave << 6)) * 8]);
        }
    };

    const int NK = K >> 6;
    stage(0, 0);
    for (int ki = 0; ki < NK; ++ki) {
        const int buf = ki & 1;
        __syncthreads();                       // drains vmcnt -> buf ready for all waves
        if (ki + 1 < NK) stage(buf ^ 1, (ki + 1) << 6);
#pragma unroll
        for (int kk = 0; kk < 2; ++kk) {
            bf16x8 af[FI], bf[FJ];
#pragma unroll
            for (int i = 0; i < FI; ++i) {
                int row = wm * WTM + i * 16 + l15;
                int slot = (kk * 4 + quad) ^ (row & 7);
                af[i] = *(const bf16x8*)&ldsA[buf][row * 64 + slot * 8];
            }
#pragma unroll
            for (int j = 0; j < FJ; ++j) {
                int row = wn * WTN + j * 16 + l15;
                int slot = (kk * 4 + quad) ^ (row & 7);
                bf[j] = *(const bf16x8*)&ldsB[buf][row * 64 + slot * 8];
            }
#pragma unroll
            for (int i = 0; i < FI; ++i)
#pragma unroll
                for (int j = 0; j < FJ; ++j)
                    acc[i][j] = __builtin_amdgcn_mfma_f32_16x16x32_bf16(af[i], bf[j], acc[i][j], 0, 0, 0);
        }
    }

#pragma unroll
    for (int i = 0; i < FI; ++i) {
        int row = tm + wm * WTM + i * 16 + quad * 4;    // C/D: row = quad*4+reg
#pragma unroll
        for (int j = 0; j < FJ; ++j) {
            int col = tn + wn * WTN + j * 16 + l15;     //      col = lane&15
            float bb = bias[col];
#pragma unroll
            for (int r = 0; r < 4; ++r) {
                float v = acc[i][j][r] + bb;
                if (resid) v += resid[(size_t)(row + r) * N + col];
                if (OUT_BF16) outb[(size_t)(row + r) * N + col] = f2b(v);
                else          outf[(size_t)(row + r) * N + col] = v;
            }
        }
    }
}

// ---------------- RoPE + bias-feature prep (reads bf16 qkv) ----------------
__global__ __launch_bounds__(256) void prep_kernel(
    const u16* __restrict__ qkv, const float* __restrict__ coords,
    const float* __restrict__ W_rope, const float* __restrict__ W_fb,
    const float* __restrict__ bcos, const float* __restrict__ bsin,
    u16* __restrict__ qe, u16* __restrict__ ke, u16* __restrict__ vt)
{
    const int bt = blockIdx.x;
    const int b = bt >> 10;
    const int t = bt & (Tc - 1);
    const float coord = coords[bt];
    const int tid = threadIdx.x;
    const u16* row = qkv + (size_t)bt * 3072;
    const int e  = tid * 4;
    const int h  = e >> 6;
    const int d0 = e & 63;
    const int m0 = d0 >> 1;

    float th0 = coord * W_rope[m0];
    float th1 = coord * W_rope[m0 + 1];
    float s0 = sinf(th0), c0 = cosf(th0);
    float s1 = sinf(th1), c1 = cosf(th1);

    float q0 = b2f(row[e]), q1 = b2f(row[e + 1]), q2 = b2f(row[e + 2]), q3 = b2f(row[e + 3]);
    float k0 = b2f(row[1024 + e]), k1 = b2f(row[1025 + e]), k2 = b2f(row[1026 + e]), k3 = b2f(row[1027 + e]);
    float v0 = b2f(row[2048 + e]), v1 = b2f(row[2049 + e]), v2 = b2f(row[2050 + e]), v3 = b2f(row[2051 + e]);

    size_t qb = ((size_t)(b * Hc + h) * Tc + t) * DE + d0;
    // q prescaled by 0.125*log2e -> scores come out of the MFMA in exp2 domain
    qe[qb + 0] = f2b((q0 * c0 - q1 * s0) * QSCALE);
    qe[qb + 1] = f2b((q0 * s0 + q1 * c0) * QSCALE);
    qe[qb + 2] = f2b((q2 * c1 - q3 * s1) * QSCALE);
    qe[qb + 3] = f2b((q2 * s1 + q3 * c1) * QSCALE);
    ke[qb + 0] = f2b(k0 * c0 - k1 * s0);
    ke[qb + 1] = f2b(k0 * s0 + k1 * c0);
    ke[qb + 2] = f2b(k2 * c1 - k3 * s1);
    ke[qb + 3] = f2b(k2 * s1 + k3 * c1);

    size_t vb = ((size_t)(b * Hc + h) * Dc + d0) * Tc + t;
    vt[vb]          = f2b(v0);
    vt[vb + Tc]     = f2b(v1);
    vt[vb + 2 * Tc] = f2b(v2);
    vt[vb + 3 * Tc] = f2b(v3);

    // bias features, spread across all 256 threads: thread = (head hh, pair s)
    {
        const int hh = tid >> 4;
        const int s  = tid & 15;
        const int m  = 2 * s;
        float thf0 = coord * W_fb[m],     thf1 = coord * W_fb[m + 1];
        float sn0 = sinf(thf0), cn0 = cosf(thf0);
        float sn1 = sinf(thf1), cn1 = cosf(thf1);
        float bc0 = bcos[m], bs0 = bsin[m], bc1 = bcos[m + 1], bs1 = bsin[m + 1];
        const float SC = 1.41421356237f * QSCALE;
        unsigned u1 = (unsigned)f2b((bc0 * cn0 + bs0 * sn0) * SC) |
                      ((unsigned)f2b((bc1 * cn1 + bs1 * sn1) * SC) << 16);
        unsigned u2 = (unsigned)f2b((bc0 * sn0 - bs0 * cn0) * SC) |
                      ((unsigned)f2b((bc1 * sn1 - bs1 * cn1) * SC) << 16);
        unsigned cp = (unsigned)f2b(cn0) | ((unsigned)f2b(cn1) << 16);
        unsigned sp = (unsigned)f2b(sn0) | ((unsigned)f2b(sn1) << 16);
        size_t base = ((size_t)(b * Hc + hh) * Tc + t) * DE + 64;
        *(unsigned*)&qe[base + m]      = u1;
        *(unsigned*)&qe[base + 32 + m] = u2;
        *(unsigned*)&ke[base + m]      = cp;
        *(unsigned*)&ke[base + 32 + m] = sp;
    }
}

// ---------------- flash attention with 32x32x16 MFMA ----------------
// grid (H*B, T/64), block 256 = 4 waves: wave = (kw = kt-half, qw = q-half).
// Each wave: 32 q-rows x 32 kt-cols per step. 32x32 frags halve ds_reads/FLOP.
// kt-halves keep independent (o,l) partials (exact under fixed-M), merged once
// at the end via LDS (ldsK space reused). l deferred in 16 regs.
// Head-major grid -> all 16 t-tiles of a head on one XCD (K/V L2 locality).
__global__ __launch_bounds__(256) void attn_kernel(
    const u16* __restrict__ qe, const u16* __restrict__ ke,
    const u16* __restrict__ vt, u16* __restrict__ yb)
{
    __shared__ u16 ldsK[2][64 * 128];  // 32 KB, swizzled (row&15)
    __shared__ u16 ldsV[2][64 * 64];   // 16 KB, swizzled (row&7)
    __shared__ u16 plds[4][32][40];    // 10 KB wave-private P (row-stride 80 B)
    __shared__ float lM[2][32];        // kt-half-1 l partials
    const int tid  = threadIdx.x;
    const int wave = tid >> 6;
    const int lane = tid & 63;
    const int l31  = lane & 31;
    const int half = lane >> 5;
    const int qw = wave & 1;           // q 32-row half
    const int kw = wave >> 1;          // kt 32-col half
    const int h  = blockIdx.x & 15;
    const int b  = blockIdx.x >> 4;
    const int qt = blockIdx.y * 64;

    const u16* Q  = qe + ((size_t)(b * Hc + h) * Tc) * DE;
    const u16* Kp = ke + ((size_t)(b * Hc + h) * Tc) * DE;
    const u16* Vp = vt + ((size_t)(b * Hc + h) * Dc) * Tc;

    // A-frag layout 32x32x16: m = lane&31, k = (lane>>5)*8 + j
    bf16x8 qf[8];
    {
        const u16* qrow = Q + (size_t)(qt + qw * 32 + l31) * DE + half * 8;
#pragma unroll
        for (int c = 0; c < 8; ++c) qf[c] = *(const bf16x8*)(qrow + c * 16);
    }

    auto stageKV = [&](int buf, int kt) {
#pragma unroll
        for (int it = 0; it < 4; ++it) {       // K: 64 rows x 16 chunks
            int p = it * 256 + tid;
            int row = p >> 4;
            int c = (p & 15) ^ (row & 15);
            gll16(Kp + (size_t)(kt + row) * DE + c * 8,
                  &ldsK[buf][(it * 256 + (wave << 6)) * 8]);
        }
#pragma unroll
        for (int it = 0; it < 2; ++it) {       // V: 64 rows x 8 chunks
            int p = it * 256 + tid;
            int row = p >> 3;
            int c = (p & 7) ^ (row & 7);
            gll16(Vp + (size_t)row * Tc + kt + c * 8,
                  &ldsV[buf][(it * 256 + (wave << 6)) * 8]);
        }
    };

    f32x16 o[2] = {};       // 2 d-tiles of 32; C/D: col=lane&31, row=(r&3)+8*(r>>2)+4*half
    float lrow[16] = {};

    stageKV(0, 0);
    for (int ki = 0; ki < Tc / 64; ++ki) {
        const int buf = ki & 1;
        __syncthreads();                       // buf ready (implicit vmcnt drain)
        if (ki + 1 < Tc / 64) stageKV(buf ^ 1, (ki + 1) * 64);

        // QK^T: S(32q x 32kt) over DE=128; B-frag: n = kt = lane&31, k = d 8-consec
        f32x16 sf = {};
#pragma unroll
        for (int c = 0; c < 8; ++c) {
            int row = kw * 32 + l31;
            int slot = (c * 2 + half) ^ (row & 15);
            bf16x8 kf = *(const bf16x8*)&ldsK[buf][row * 128 + slot * 8];
            sf = __builtin_amdgcn_mfma_f32_32x32x16_bf16(qf[c], kf, sf, 0, 0, 0);
        }
        // p = exp2(s - M); store P[q][kt] for A-frag reuse, accumulate l in regs
#pragma unroll
        for (int r = 0; r < 16; ++r) {
            float p = __builtin_amdgcn_exp2f(sf[r] - FIXED_M);
            u16 tp = (u16)(__float_as_uint(p) >> 16);
            int row = (r & 3) + 8 * (r >> 2) + 4 * half;
            plds[wave][row][l31] = tp;
            lrow[r] += b2f(tp);
        }
        // PV: O(32q x 64d) over 32 kt; A = P (row q = lane&31, kt 8-consec),
        // B = V^T (row d = dt*32 + lane&31, kt 8-consec)
#pragma unroll
        for (int kc = 0; kc < 2; ++kc) {
            bf16x8 pa = *(const bf16x8*)&plds[wave][l31][kc * 16 + half * 8];
#pragma unroll
            for (int dt = 0; dt < 2; ++dt) {
                int vrow = dt * 32 + l31;
                int chunk = (kw * 32 + kc * 16 + half * 8) >> 3;
                int slot = chunk ^ (vrow & 7);
                bf16x8 vf = *(const bf16x8*)&ldsV[buf][vrow * 64 + slot * 8];
                o[dt] = __builtin_amdgcn_mfma_f32_32x32x16_bf16(pa, vf, o[dt], 0, 0, 0);
            }
        }
    }

    __syncthreads();   // all LDS reads done before reusing ldsK as merge space

    // reduce each lrow reg across its 32-lane column group
#pragma unroll
    for (int r = 0; r < 16; ++r) {
        float v = lrow[r];
#pragma unroll
        for (int off = 1; off < 32; off <<= 1) v += __shfl_xor(v, off);
        lrow[r] = v;
    }

    float* oM = (float*)&ldsK[0][0];   // [qw][32 q][64 d] = 16 KB
    if (kw == 1) {
#pragma unroll
        for (int r = 0; r < 16; ++r) {
            int row = (r & 3) + 8 * (r >> 2) + 4 * half;
#pragma unroll
            for (int dt = 0; dt < 2; ++dt)
                oM[(qw * 32 + row) * 64 + dt * 32 + l31] = o[dt][r];
            if (l31 == 0) lM[qw][row] = lrow[r];
        }
    }
    __syncthreads();
    if (kw == 0) {
#pragma unroll
        for (int r = 0; r < 16; ++r) {
            int row = (r & 3) + 8 * (r >> 2) + 4 * half;
            float rl = 1.0f / (lrow[r] + lM[qw][row]);
            int t = qt + qw * 32 + row;
#pragma unroll
            for (int dt = 0; dt < 2; ++dt) {
                float val = (o[dt][r] + oM[(qw * 32 + row) * 64 + dt * 32 + l31]) * rl;
                yb[((size_t)b * Tc + t) * Cc + h * Dc + dt * 32 + l31] = f2b(val);
            }
        }
    }
}

extern "C" void kernel_launch(void* const* d_in, const int* in_sizes, int n_in,
                              void* d_out, int out_size, void* d_ws, size_t ws_size,
                              hipStream_t stream) {
    const float* x      = (const float*)d_in[0];
    const float* coords = (const float*)d_in[1];
    const float* W_attn = (const float*)d_in[2];
    const float* b_attn = (const float*)d_in[3];
    const float* W_proj = (const float*)d_in[4];
    const float* b_proj = (const float*)d_in[5];
    const float* W_rope = (const float*)d_in[6];
    const float* W_fb   = (const float*)d_in[7];
    const float* bcos   = (const float*)d_in[8];
    const float* bsin   = (const float*)d_in[9];
    float* out = (float*)d_out;

    char* w = (char*)d_ws;
    const size_t MB = 1024 * 1024;
    u16* xb     = (u16*)(w + 0);          //  4 MB: x bf16
    u16* wab    = (u16*)(w + 4 * MB);     //  6 MB: W_attn bf16
    u16* wpb    = (u16*)(w + 10 * MB);    //  2 MB: W_proj bf16
    u16* qkvb16 = (u16*)(w + 12 * MB);    // 12 MB: qkv bf16
    u16* qext   = (u16*)(w + 24 * MB);    //  8 MB: q_ext (prescaled)
    u16* kext   = (u16*)(w + 32 * MB);    //  8 MB: k_ext
    u16* vtw    = (u16*)(w + 40 * MB);    //  4 MB: v^T
    u16* yb     = (u16*)(w + 44 * MB);    //  4 MB: attn out bf16

    const int NALL = (Bc * Tc * Cc + 3 * Cc * Cc + Cc * Cc) / 4;
    cast_all<<<NALL / 256, 256, 0, stream>>>(x, W_attn, W_proj, xb, wab, wpb);

    // 64x128 tile: 768 blocks = 3/CU exact, 48 KB LDS -> 3 blocks/CU resident
    dim3 g1(3 * Cc / 128, Bc * Tc / 64);
    gemm_abt<64, 128, 2, 2, true><<<g1, 256, 0, stream>>>(
        xb, wab, b_attn, nullptr, nullptr, qkvb16, Bc * Tc, 3 * Cc, Cc);

    prep_kernel<<<Bc * Tc, 256, 0, stream>>>(qkvb16, coords, W_rope, W_fb, bcos, bsin, qext, kext, vtw);

    dim3 g2(Hc * Bc, Tc / 64);
    attn_kernel<<<g2, 256, 0, stream>>>(qext, kext, vtw, yb);

    dim3 g3(Cc / 64, Bc * Tc / 64);
    gemm_abt<64, 64, 2, 2, false><<<g3, 256, 0, stream>>>(
        yb, wpb, b_proj, x, out, nullptr, Bc * Tc, Cc, Cc);
}